// Round 7
// baseline (190.358 us; speedup 1.0000x reference)
//
#include <hip/hip_runtime.h>

typedef unsigned short u16;
typedef unsigned int   u32;
typedef short  short8  __attribute__((ext_vector_type(8)));
typedef __bf16 bf16x8  __attribute__((ext_vector_type(8)));
typedef float  f32x4   __attribute__((ext_vector_type(4)));
typedef u32    u32x4   __attribute__((ext_vector_type(4)));

#define POWER_ITERS 3

// ---------- helpers ----------
__device__ __forceinline__ u16 f2bf(float f){ return __builtin_bit_cast(u16, (__bf16)f); }
__device__ __forceinline__ u32 pack2bf(float a, float b){
  return (u32)__builtin_bit_cast(u16, (__bf16)a) | ((u32)__builtin_bit_cast(u16, (__bf16)b) << 16);
}
__device__ __forceinline__ float bf2f(u16 h){ return __uint_as_float(((u32)h) << 16); }

__device__ __forceinline__ f32x4 mfma_bf16(short8 a, short8 b, f32x4 c){
  return __builtin_amdgcn_mfma_f32_16x16x32_bf16(
      __builtin_bit_cast(bf16x8, a), __builtin_bit_cast(bf16x8, b), c, 0, 0, 0);
}

// swizzled LDS address (u16 units) of element [row][k] of a 64x64 matrix
__device__ __forceinline__ int swz(int row, int k){
  return row*64 + ((((k >> 3) ^ (row & 7)) << 3) | (k & 7));
}
__device__ __forceinline__ short8 lds_frag(const u16* P, int row, int k0){
  int pos = (k0 >> 3) ^ (row & 7);
  return *(const short8*)(P + row*64 + pos*8);
}
__device__ __forceinline__ short8 g_frag(const u16* __restrict__ M, int row, int k0){
  return *(const short8*)(M + row*64 + k0);
}

// write C/D regs (matrix X, C-layout) as X^T into swizzled LDS (Zt format), scaled
__device__ __forceinline__ void write_CT_lds_s(u16* Pt, int lane, const f32x4 (&C)[4][4], float s){
  const int m16 = lane & 15, q = lane >> 4;
#pragma unroll
  for(int i = 0; i < 4; i++){
    const int r0 = i*16 + q*4;
#pragma unroll
    for(int j = 0; j < 4; j++){
      const int c = j*16 + m16;
      const int addr = c*64 + ((((r0 >> 3) ^ (c & 7)) << 3) | (r0 & 7));
      u32 lo = pack2bf(C[i][j][0]*s, C[i][j][1]*s);
      u32 hi = pack2bf(C[i][j][2]*s, C[i][j][3]*s);
      *(uint2*)(Pt + addr) = make_uint2(lo, hi);
    }
  }
}
__device__ __forceinline__ void write_CT_lds(u16* Pt, int lane, const f32x4 (&C)[4][4]){
  write_CT_lds_s(Pt, lane, C, 1.f);
}

// write C (matrix X, C-layout) ROW-MAJOR swizzled (Zn format), scaled — scalar scatter
__device__ __forceinline__ void scatter_C_rm(u16* Z, int lane, const f32x4 (&C)[4][4], float s){
  const int m16 = lane & 15, q = lane >> 4;
#pragma unroll
  for(int i = 0; i < 4; i++)
#pragma unroll
    for(int j = 0; j < 4; j++)
#pragma unroll
      for(int t = 0; t < 4; t++)
        Z[swz(i*16 + q*4 + t, j*16 + m16)] = f2bf(C[i][j][t]*s);
}

// C = A (regs) * P (Pt = Zt of P); optional write of C^T back into Pt
__device__ __forceinline__ void chain_step_A(const short8 (&Af)[2][4], u16* Pt, int lane,
                                             f32x4 (&C)[4][4], bool wb){
  const int m16 = lane & 15, q = lane >> 4;
  short8 Bf[2][4];
#pragma unroll
  for(int ks = 0; ks < 2; ks++)
#pragma unroll
    for(int t = 0; t < 4; t++) Bf[ks][t] = lds_frag(Pt, t*16 + m16, ks*32 + q*8);
#pragma unroll
  for(int i = 0; i < 4; i++)
#pragma unroll
    for(int j = 0; j < 4; j++) C[i][j] = f32x4{0.f,0.f,0.f,0.f};
#pragma unroll
  for(int ks = 0; ks < 2; ks++)
#pragma unroll
    for(int i = 0; i < 4; i++)
#pragma unroll
      for(int j = 0; j < 4; j++)
        C[i][j] = mfma_bf16(Af[ks][i], Bf[ks][j], C[i][j]);
  if(wb) write_CT_lds(Pt, lane, C);
}

// A-frags (rows) from a Zn-format LDS zone
__device__ __forceinline__ void ld_zn_frags(const u16* Zn, int m16, int q, short8 (&Af)[2][4]){
#pragma unroll
  for(int ks = 0; ks < 2; ks++)
#pragma unroll
    for(int t = 0; t < 4; t++) Af[ks][t] = lds_frag(Zn, t*16 + m16, ks*32 + q*8);
}
// A-frags from row-major bf16 global
__device__ __forceinline__ void ld_bf16_frags(const u16* __restrict__ M, int m16, int q, short8 (&Af)[2][4]){
#pragma unroll
  for(int ks = 0; ks < 2; ks++)
#pragma unroll
    for(int t = 0; t < 4; t++) Af[ks][t] = g_frag(M, t*16 + m16, ks*32 + q*8);
}

// P = N (global row-major bf16) -> Zt of P
__device__ __forceinline__ void load_Pt_transpose(const u16* __restrict__ N, u16* Pt, int lane){
#pragma unroll
  for(int g = 0; g < 8; g++){
    short8 v = *(const short8*)(N + lane*64 + g*8);
#pragma unroll
    for(int t = 0; t < 8; t++) Pt[swz(g*8 + t, lane)] = (u16)v[t];
  }
}

__device__ __forceinline__ float wave_max(float mx){
  for(int off = 32; off; off >>= 1) mx = fmaxf(mx, __shfl_xor(mx, off, 64));
  return mx;
}
__device__ __forceinline__ int norm_es(const f32x4 (&C)[4][4], float& s){
  float mx = 0.f;
#pragma unroll
  for(int i = 0; i < 4; i++)
#pragma unroll
    for(int j = 0; j < 4; j++)
#pragma unroll
      for(int t = 0; t < 4; t++) mx = fmaxf(mx, C[i][j][t]);   // entries all positive
  mx = wave_max(mx);
  int e; (void)frexpf(mx, &e);
  s = ldexpf(1.f, -e);
  return e;
}

// power-iteration stages (one Kraus op per wave, K frags in regs)
__device__ __forceinline__ void pw_stages(const short8 (&Kf)[2][4], const u16* rho, u16* zw,
                                          int m16, int q, int lane){
  short8 Ar[2][4];
#pragma unroll
  for(int ks = 0; ks < 2; ks++)
#pragma unroll
    for(int t = 0; t < 4; t++) Ar[ks][t] = lds_frag(rho, t*16 + m16, ks*32 + q*8);
  f32x4 C[4][4];
#pragma unroll
  for(int i = 0; i < 4; i++)
#pragma unroll
    for(int j = 0; j < 4; j++) C[i][j] = f32x4{0.f,0.f,0.f,0.f};
#pragma unroll
  for(int ks = 0; ks < 2; ks++)
#pragma unroll
    for(int i = 0; i < 4; i++)
#pragma unroll
      for(int j = 0; j < 4; j++)
        C[i][j] = mfma_bf16(Ar[ks][i], Kf[ks][j], C[i][j]);
  write_CT_lds(zw, lane, C);            // zw = Kw*rho (rho symmetric)
  short8 Bt[2][4];
#pragma unroll
  for(int ks = 0; ks < 2; ks++)
#pragma unroll
    for(int t = 0; t < 4; t++) Bt[ks][t] = lds_frag(zw, t*16 + m16, ks*32 + q*8);
#pragma unroll
  for(int i = 0; i < 4; i++)
#pragma unroll
    for(int j = 0; j < 4; j++) C[i][j] = f32x4{0.f,0.f,0.f,0.f};
#pragma unroll
  for(int ks = 0; ks < 2; ks++)
#pragma unroll
    for(int i = 0; i < 4; i++)
#pragma unroll
      for(int j = 0; j < 4; j++)
        C[i][j] = mfma_bf16(Kf[ks][i], Bt[ks][j], C[i][j]);
  write_CT_lds(zw, lane, C);            // zone_w = Kw*rho*Kw^T
}

// grid barrier: counter zeroed by hipMemsetAsync before launch; 256 blocks co-resident (1/CU)
__device__ __forceinline__ void gridbar(int* c){
  __threadfence();
  __syncthreads();
  if(threadIdx.x == 0){
    atomicAdd(c, 1);
    while(*((volatile int*)c) < 256) __builtin_amdgcn_s_sleep(2);
    __threadfence();
  }
  __syncthreads();
}

// ==================== the single kernel ====================
__global__ __launch_bounds__(512, 2) void kall(const float* __restrict__ K, const int* __restrict__ seq,
                                               u16* __restrict__ Nbuf, u16* __restrict__ M2buf,
                                               int* __restrict__ Sarr, int* __restrict__ Earr,
                                               float* __restrict__ rhoR, float* __restrict__ rhoL,
                                               float* __restrict__ muv, int* __restrict__ bar,
                                               float* __restrict__ outp){
  __shared__ __align__(16) u16 Kl[8*4096];     // bf16 K matrices (Zn swizzled)
  __shared__ __align__(16) u16 zones[8*4096];  // per-wave work zones
  __shared__ __align__(16) u16 rhoZ[4096];     // power-iteration rho
  __shared__ float redf[8];
  __shared__ int exps[8];
  __shared__ float sh_t2;
  __shared__ int sh_S;
  const int tid = threadIdx.x, lane = tid & 63, wave = tid >> 6, b = blockIdx.x;
  const int m16 = lane & 15, q = lane >> 4;
  u16* zw = zones + wave*4096;

  // ===================== PHASE A (all blocks): 64 seq-mats -> 1 node =====================
  {
    // stage K[wave] fp32 -> Kl zone (Zn swizzled); lane owns row = lane
#pragma unroll
    for(int g = 0; g < 8; g++){
      const float* p = K + (size_t)wave*4096 + lane*64 + g*8;
      float4 a = *(const float4*)p, c = *(const float4*)(p + 4);
      u32x4 u = { pack2bf(a.x,a.y), pack2bf(a.z,a.w), pack2bf(c.x,c.y), pack2bf(c.z,c.w) };
      *(short8*)(Kl + wave*4096 + lane*64 + ((g ^ (lane & 7)) << 3)) = __builtin_bit_cast(short8, u);
    }
    int sv = (lane < 8) ? seq[(b*8 + wave)*8 + lane] : 0;
    __syncthreads();
    // Pt init: Zt of Kl[s0]
    int s0 = __shfl(sv, 0, 64);
    {
      const u16* Z = Kl + s0*4096;
#pragma unroll
      for(int g = 0; g < 8; g++){
        short8 f = lds_frag(Z, lane, g*8);
#pragma unroll
        for(int j = 0; j < 8; j++) zw[swz(g*8 + j, lane)] = (u16)f[j];
      }
    }
    f32x4 C[4][4];
    short8 Af[2][4];
#pragma unroll 1
    for(int j = 1; j < 8; j++){
      int sj = __shfl(sv, j, 64);
      ld_zn_frags(Kl + sj*4096, m16, q, Af);
      chain_step_A(Af, zw, lane, C, j < 7);
    }
    float s; int e = norm_es(C, s);
    if(!(wave & 1)) write_CT_lds_s(zw, lane, C, s);   // even wave -> Zt
    else            scatter_C_rm(zw, lane, C, s);     // odd wave  -> Zn
    if(lane == 0) exps[wave] = e;
    __syncthreads();
    if(wave < 4){                                      // combine L1
      short8 Aa[2][4];
      ld_zn_frags(zones + (2*wave + 1)*4096, m16, q, Aa);
      f32x4 Y[4][4];
      bool e2 = !(wave & 1);
      chain_step_A(Aa, zones + 2*wave*4096, lane, Y, e2);
      if(!e2) scatter_C_rm(zones + 2*wave*4096, lane, Y, 1.f);
    }
    __syncthreads();
    if(wave < 2){                                      // combine L2
      short8 Aa[2][4];
      ld_zn_frags(zones + (4*wave + 2)*4096, m16, q, Aa);
      f32x4 Y[4][4];
      chain_step_A(Aa, zones + 4*wave*4096, lane, Y, wave == 0);
      if(wave == 1) scatter_C_rm(zones + 4*4096, lane, Y, 1.f);
    }
    __syncthreads();
    if(wave == 0){                                     // combine L3 + norm
      short8 Aa[2][4];
      ld_zn_frags(zones + 4*4096, m16, q, Aa);
      f32x4 M[4][4];
      chain_step_A(Aa, zones, lane, M, false);
      float sr; int er = norm_es(M, sr);
      scatter_C_rm(zones, lane, M, sr);
      if(lane == 0){
        int ss = er;
#pragma unroll
        for(int w = 0; w < 8; w++) ss += exps[w];
        Sarr[b] = ss;
      }
    }
    __syncthreads();
    {
      int row = tid >> 3, c0 = (tid & 7)*8;
      *(short8*)(Nbuf + (size_t)b*4096 + row*64 + c0) = lds_frag(zones, row, c0);
    }
  }
  gridbar(bar);

  // ===================== PHASE B =====================
  if(b < 2){
    // power iteration (b0: right, b1: left); K frags from LDS copy
    const bool left = (b == 1);
    short8 Kf[2][4];
    if(!left){
      ld_zn_frags(Kl + wave*4096, m16, q, Kf);
    } else {
#pragma unroll
      for(int ks = 0; ks < 2; ks++)
#pragma unroll
        for(int t = 0; t < 4; t++){
          short8 v;
#pragma unroll
          for(int j = 0; j < 8; j++) v[j] = (short)Kl[wave*4096 + swz(ks*32 + q*8 + j, t*16 + m16)];
          Kf[ks][t] = v;
        }
    }
    const int row = tid >> 3, k0 = (tid & 7)*8;
    const int rpos = row*64 + (((tid & 7) ^ (row & 7)) << 3);
    {
      short8 bb;
#pragma unroll
      for(int j = 0; j < 8; j++) bb[j] = (row == k0 + j) ? (short)f2bf(1.f/64.f) : (short)0;
      *(short8*)(rhoZ + rpos) = bb;
    }
    __syncthreads();
    const float S13 = 1.f/8192.f;        // fixed per-iter scale (lambda ~ 2^13)
#pragma unroll
    for(int it = 0; it < POWER_ITERS; it++){
      pw_stages(Kf, rhoZ, zw, m16, q, lane);
      __syncthreads();
      float v[8];
#pragma unroll
      for(int j2 = 0; j2 < 8; j2++) v[j2] = 0.f;
#pragma unroll
      for(int z = 0; z < 8; z++){
        short8 f = lds_frag(zones + z*4096, row, k0);
#pragma unroll
        for(int j2 = 0; j2 < 8; j2++) v[j2] += bf2f((u16)f[j2]);
      }
      if(it != POWER_ITERS - 1){
        u32x4 u = { pack2bf(v[0]*S13, v[1]*S13), pack2bf(v[2]*S13, v[3]*S13),
                    pack2bf(v[4]*S13, v[5]*S13), pack2bf(v[6]*S13, v[7]*S13) };
        *(short8*)(rhoZ + rpos) = __builtin_bit_cast(short8, u);
        __syncthreads();
      } else {
        float pd = (k0 <= row && row < k0 + 8) ? v[row - k0] : 0.f;
        for(int off = 32; off; off >>= 1) pd += __shfl_xor(pd, off, 64);
        if(lane == 0) redf[wave] = pd;
        __syncthreads();
        float tr = 0.f;
#pragma unroll
        for(int w = 0; w < 8; w++) tr += redf[w];
        float inv = 1.f/tr;
        float* ro = left ? rhoL : rhoR;
#pragma unroll
        for(int j2 = 0; j2 < 8; j2++) ro[row*64 + k0 + j2] = v[j2]*inv;
        u32x4 u = { pack2bf(v[0]*inv, v[1]*inv), pack2bf(v[2]*inv, v[3]*inv),
                    pack2bf(v[4]*inv, v[5]*inv), pack2bf(v[6]*inv, v[7]*inv) };
        *(short8*)(rhoZ + rpos) = __builtin_bit_cast(short8, u);   // normalized bf16 kept in LDS
      }
    }
    __syncthreads();
    if(left){
      // lambda = tr(rho_l * sum_a K_a K_a^T); wave a handles K_a
      short8 Ka[2][4];
      ld_zn_frags(Kl + wave*4096, m16, q, Ka);
      f32x4 G[4][4];
#pragma unroll
      for(int i = 0; i < 4; i++)
#pragma unroll
        for(int j = 0; j < 4; j++) G[i][j] = f32x4{0.f,0.f,0.f,0.f};
#pragma unroll
      for(int ks = 0; ks < 2; ks++)
#pragma unroll
        for(int i = 0; i < 4; i++)
#pragma unroll
          for(int j = 0; j < 4; j++)
            G[i][j] = mfma_bf16(Ka[ks][i], Ka[ks][j], G[i][j]);   // G_a = K_a K_a^T
      float lp = 0.f;
#pragma unroll
      for(int i = 0; i < 4; i++)
#pragma unroll
        for(int j = 0; j < 4; j++)
#pragma unroll
          for(int t = 0; t < 4; t++){
            int r = i*16 + q*4 + t, c = j*16 + m16;
            lp += G[i][j][t] * bf2f(rhoZ[swz(r, c)]);
          }
      for(int off = 32; off; off >>= 1) lp += __shfl_xor(lp, off, 64);
      if(lane == 0) redf[wave] = lp;
      __syncthreads();
      if(tid == 0){
        float m = 0.f;
#pragma unroll
        for(int w = 0; w < 8; w++) m += redf[w];
        muv[0] = m;
      }
    }
  } else if(b < 18){
    // combine 16 Nbuf nodes -> one M2 node
    const int nb = (b - 2)*16;
    short8 Af[2][4];
    ld_bf16_frags(Nbuf + (size_t)(nb + 2*wave + 1)*4096, m16, q, Af);
    load_Pt_transpose(Nbuf + (size_t)(nb + 2*wave)*4096, zw, lane);
    f32x4 C[4][4];
    bool ev = !(wave & 1);
    chain_step_A(Af, zw, lane, C, ev);
    if(!ev) scatter_C_rm(zw, lane, C, 1.f);
    __syncthreads();
    if(wave < 4){
      short8 Aa[2][4];
      ld_zn_frags(zones + (2*wave + 1)*4096, m16, q, Aa);
      f32x4 Y[4][4];
      bool e2 = !(wave & 1);
      chain_step_A(Aa, zones + 2*wave*4096, lane, Y, e2);
      if(!e2) scatter_C_rm(zones + 2*wave*4096, lane, Y, 1.f);
    }
    __syncthreads();
    if(wave < 2){
      short8 Aa[2][4];
      ld_zn_frags(zones + (4*wave + 2)*4096, m16, q, Aa);
      f32x4 Y[4][4];
      chain_step_A(Aa, zones + 4*wave*4096, lane, Y, wave == 0);
      if(wave == 1) scatter_C_rm(zones + 4*4096, lane, Y, 1.f);
    }
    __syncthreads();
    if(wave == 0){
      short8 Aa[2][4];
      ld_zn_frags(zones + 4*4096, m16, q, Aa);
      f32x4 M[4][4];
      chain_step_A(Aa, zones, lane, M, false);
      float sr; int er = norm_es(M, sr);
      scatter_C_rm(zones, lane, M, sr);
      if(lane == 0) Earr[b - 2] = er;
    }
    __syncthreads();
    {
      int row = tid >> 3, c0 = (tid & 7)*8;
      *(short8*)(M2buf + (size_t)(b - 2)*4096 + row*64 + c0) = lds_frag(zones, row, c0);
    }
  }
  gridbar(bar + 1);

  // ===================== PHASE C (block 0 only) =====================
  if(b == 0){
    // pair step: wave w: X_w = M2[2w+1]*M2[2w]
    short8 Af[2][4];
    f32x4 C[4][4];
    ld_bf16_frags(M2buf + (size_t)(2*wave + 1)*4096, m16, q, Af);
    load_Pt_transpose(M2buf + (size_t)(2*wave)*4096, zw, lane);
    bool ev = !(wave & 1);
    chain_step_A(Af, zw, lane, C, ev);
    if(!ev) scatter_C_rm(zw, lane, C, 1.f);
    __syncthreads();
    // L1 (waves 0-3) + side jobs (waves 4-6)
    if(wave < 4){
      short8 Aa[2][4];
      ld_zn_frags(zones + (2*wave + 1)*4096, m16, q, Aa);
      f32x4 Y[4][4];
      bool e2 = !(wave & 1);
      chain_step_A(Aa, zones + 2*wave*4096, lane, Y, e2);
      if(!e2) scatter_C_rm(zones + 2*wave*4096, lane, Y, 1.f);
    } else if(wave == 4){
      // rho_l fp32 global -> bf16 swizzled at Kl+4096
#pragma unroll
      for(int g = 0; g < 8; g++){
        const float* p = rhoL + lane*64 + g*8;
        float4 a = *(const float4*)p, c = *(const float4*)(p + 4);
        u32x4 u = { pack2bf(a.x,a.y), pack2bf(a.z,a.w), pack2bf(c.x,c.y), pack2bf(c.z,c.w) };
        *(short8*)(Kl + 4096 + lane*64 + ((g ^ (lane & 7)) << 3)) = __builtin_bit_cast(short8, u);
      }
    } else if(wave == 5){
      float t2 = 0.f;
      for(int j = 0; j < 64; j++){
        int idx = lane + 64*j;
        t2 += rhoR[idx] * rhoL[idx];
      }
      for(int off = 32; off; off >>= 1) t2 += __shfl_xor(t2, off, 64);
      if(lane == 0) sh_t2 = t2;
    } else if(wave == 6){
      int s = (lane < 16) ? Earr[lane] : 0;
#pragma unroll
      for(int kk = 0; kk < 4; kk++) s += Sarr[lane + 64*kk];
      for(int off = 32; off; off >>= 1) s += __shfl_xor(s, off, 64);
      if(lane == 0) sh_S = s;
    }
    __syncthreads();
    if(wave < 2){
      short8 Aa[2][4];
      ld_zn_frags(zones + (4*wave + 2)*4096, m16, q, Aa);
      f32x4 Y[4][4];
      chain_step_A(Aa, zones + 4*wave*4096, lane, Y, wave == 0);
      if(wave == 1) scatter_C_rm(zones + 4*4096, lane, Y, 1.f);
    }
    __syncthreads();
    if(wave == 0){
      // L3 -> M
      short8 Aa[2][4];
      ld_zn_frags(zones + 4*4096, m16, q, Aa);
      chain_step_A(Aa, zones, lane, C, false);
      float sM; int eM = norm_es(C, sM);
      u16* Pm = zones + 1*4096;                 // free after L1
      scatter_C_rm(Pm, lane, C, sM);

      // U = M * rho_r  (rho_r bf16 in rhoZ, symmetric)
      short8 Ua[2][4], Ub[2][4];
      ld_zn_frags(Pm, m16, q, Ua);
      ld_zn_frags(rhoZ, m16, q, Ub);
#pragma unroll
      for(int i = 0; i < 4; i++)
#pragma unroll
        for(int j = 0; j < 4; j++) C[i][j] = f32x4{0.f,0.f,0.f,0.f};
#pragma unroll
      for(int ks = 0; ks < 2; ks++)
#pragma unroll
        for(int i = 0; i < 4; i++)
#pragma unroll
          for(int j = 0; j < 4; j++)
            C[i][j] = mfma_bf16(Ua[ks][i], Ub[ks][j], C[i][j]);
      write_CT_lds(zones + 3*4096, lane, C);    // U^T

      // D2 = rho_l * U
      ld_zn_frags(Kl + 4096, m16, q, Ua);
#pragma unroll
      for(int ks = 0; ks < 2; ks++)
#pragma unroll
        for(int t = 0; t < 4; t++) Ub[ks][t] = lds_frag(zones + 3*4096, t*16 + m16, ks*32 + q*8);
#pragma unroll
      for(int i = 0; i < 4; i++)
#pragma unroll
        for(int j = 0; j < 4; j++) C[i][j] = f32x4{0.f,0.f,0.f,0.f};
#pragma unroll
      for(int ks = 0; ks < 2; ks++)
#pragma unroll
        for(int i = 0; i < 4; i++)
#pragma unroll
          for(int j = 0; j < 4; j++)
            C[i][j] = mfma_bf16(Ua[ks][i], Ub[ks][j], C[i][j]);

      // t1 = sum_ij D2_ij * M_ij
      float part = 0.f;
#pragma unroll
      for(int i = 0; i < 4; i++)
#pragma unroll
        for(int j = 0; j < 4; j++)
#pragma unroll
          for(int t = 0; t < 4; t++){
            int r = i*16 + q*4 + t, c = j*16 + m16;
            part += C[i][j][t] * bf2f(Pm[swz(r, c)]);
          }
      for(int off = 32; off; off >>= 1) part += __shfl_xor(part, off, 64);
      if(lane == 0){
        double t1  = (double)part;
        double lam = (double)muv[0];
        double S   = (double)sh_S + eM;
        double logp = 16384.0*log2(lam) - 2.0*S - log2(t1) + log2((double)sh_t2);
        outp[0] = (float)logp;
      }
    }
  }
}

// ---------- launch ----------
extern "C" void kernel_launch(void* const* d_in, const int* in_sizes, int n_in,
                              void* d_out, int out_size, void* d_ws, size_t ws_size,
                              hipStream_t stream) {
  const float* K  = (const float*)d_in[0];   // (8,64,64) fp32
  const int* seq  = (const int*)d_in[1];     // (16384,) int32
  char* ws = (char*)d_ws;
  u16*   Nbuf  = (u16*)(ws);                   // 256 * 8KB = 2 MB
  u16*   M2buf = (u16*)(ws + 2097152);         // 16 * 8KB = 128 KB
  int*   Sarr  = (int*)(ws + 2228224);         // 256 ints
  int*   Earr  = (int*)(ws + 2229248);         // 16 ints
  float* rhoR  = (float*)(ws + 2229312);       // 16 KB
  float* rhoL  = (float*)(ws + 2245696);       // 16 KB
  float* muv   = (float*)(ws + 2262080);       // 1 float
  int*   bar   = (int*)(ws + 2262144);         // 2 ints (grid barrier counters)

  hipMemsetAsync(bar, 0, 8, stream);
  kall<<<256, 512, 0, stream>>>(K, seq, Nbuf, M2buf, Sarr, Earr, rhoR, rhoL, muv, bar,
                                (float*)d_out);
}

// Round 8
// 109.178 us; speedup vs baseline: 1.7436x; 1.7436x over previous
//
#include <hip/hip_runtime.h>

typedef unsigned short u16;
typedef unsigned int   u32;
typedef short  short8  __attribute__((ext_vector_type(8)));
typedef __bf16 bf16x8  __attribute__((ext_vector_type(8)));
typedef float  f32x4   __attribute__((ext_vector_type(4)));
typedef u32    u32x4   __attribute__((ext_vector_type(4)));

#define POWER_ITERS 3

// ---------- helpers ----------
__device__ __forceinline__ u16 f2bf(float f){ return __builtin_bit_cast(u16, (__bf16)f); }
__device__ __forceinline__ u32 pack2bf(float a, float b){
  return (u32)__builtin_bit_cast(u16, (__bf16)a) | ((u32)__builtin_bit_cast(u16, (__bf16)b) << 16);
}
__device__ __forceinline__ float bf2f(u16 h){ return __uint_as_float(((u32)h) << 16); }

__device__ __forceinline__ f32x4 mfma_bf16(short8 a, short8 b, f32x4 c){
  return __builtin_amdgcn_mfma_f32_16x16x32_bf16(
      __builtin_bit_cast(bf16x8, a), __builtin_bit_cast(bf16x8, b), c, 0, 0, 0);
}

// swizzled LDS address (u16 units) of element [row][k] of a 64x64 matrix
__device__ __forceinline__ int swz(int row, int k){
  return row*64 + ((((k >> 3) ^ (row & 7)) << 3) | (k & 7));
}
__device__ __forceinline__ short8 lds_frag(const u16* P, int row, int k0){
  int pos = (k0 >> 3) ^ (row & 7);
  return *(const short8*)(P + row*64 + pos*8);
}
__device__ __forceinline__ short8 g_frag(const u16* __restrict__ M, int row, int k0){
  return *(const short8*)(M + row*64 + k0);
}

// write C/D regs (matrix X, C-layout) as X^T into swizzled LDS (Zt format), scaled
__device__ __forceinline__ void write_CT_lds_s(u16* Pt, int lane, const f32x4 (&C)[4][4], float s){
  const int m16 = lane & 15, q = lane >> 4;
#pragma unroll
  for(int i = 0; i < 4; i++){
    const int r0 = i*16 + q*4;
#pragma unroll
    for(int j = 0; j < 4; j++){
      const int c = j*16 + m16;
      const int addr = c*64 + ((((r0 >> 3) ^ (c & 7)) << 3) | (r0 & 7));
      u32 lo = pack2bf(C[i][j][0]*s, C[i][j][1]*s);
      u32 hi = pack2bf(C[i][j][2]*s, C[i][j][3]*s);
      *(uint2*)(Pt + addr) = make_uint2(lo, hi);
    }
  }
}
__device__ __forceinline__ void write_CT_lds(u16* Pt, int lane, const f32x4 (&C)[4][4]){
  write_CT_lds_s(Pt, lane, C, 1.f);
}

// write C (matrix X, C-layout) ROW-MAJOR swizzled (Zn format), scaled — scalar scatter
__device__ __forceinline__ void scatter_C_rm(u16* Z, int lane, const f32x4 (&C)[4][4], float s){
  const int m16 = lane & 15, q = lane >> 4;
#pragma unroll
  for(int i = 0; i < 4; i++)
#pragma unroll
    for(int j = 0; j < 4; j++)
#pragma unroll
      for(int t = 0; t < 4; t++)
        Z[swz(i*16 + q*4 + t, j*16 + m16)] = f2bf(C[i][j][t]*s);
}

// C = A (regs) * P (Pt = Zt of P); optional write of C^T back into Pt
__device__ __forceinline__ void chain_step_A(const short8 (&Af)[2][4], u16* Pt, int lane,
                                             f32x4 (&C)[4][4], bool wb){
  const int m16 = lane & 15, q = lane >> 4;
  short8 Bf[2][4];
#pragma unroll
  for(int ks = 0; ks < 2; ks++)
#pragma unroll
    for(int t = 0; t < 4; t++) Bf[ks][t] = lds_frag(Pt, t*16 + m16, ks*32 + q*8);
#pragma unroll
  for(int i = 0; i < 4; i++)
#pragma unroll
    for(int j = 0; j < 4; j++) C[i][j] = f32x4{0.f,0.f,0.f,0.f};
#pragma unroll
  for(int ks = 0; ks < 2; ks++)
#pragma unroll
    for(int i = 0; i < 4; i++)
#pragma unroll
      for(int j = 0; j < 4; j++)
        C[i][j] = mfma_bf16(Af[ks][i], Bf[ks][j], C[i][j]);
  if(wb) write_CT_lds(Pt, lane, C);
}

// A-frags (rows) from a Zn-format LDS zone
__device__ __forceinline__ void ld_zn_frags(const u16* Zn, int m16, int q, short8 (&Af)[2][4]){
#pragma unroll
  for(int ks = 0; ks < 2; ks++)
#pragma unroll
    for(int t = 0; t < 4; t++) Af[ks][t] = lds_frag(Zn, t*16 + m16, ks*32 + q*8);
}
// A-frags from row-major bf16 global
__device__ __forceinline__ void ld_bf16_frags(const u16* __restrict__ M, int m16, int q, short8 (&Af)[2][4]){
#pragma unroll
  for(int ks = 0; ks < 2; ks++)
#pragma unroll
    for(int t = 0; t < 4; t++) Af[ks][t] = g_frag(M, t*16 + m16, ks*32 + q*8);
}

// P = N (global row-major bf16) -> Zt of P
__device__ __forceinline__ void load_Pt_transpose(const u16* __restrict__ N, u16* Pt, int lane){
#pragma unroll
  for(int g = 0; g < 8; g++){
    short8 v = *(const short8*)(N + lane*64 + g*8);
#pragma unroll
    for(int t = 0; t < 8; t++) Pt[swz(g*8 + t, lane)] = (u16)v[t];
  }
}
// Pt <- Zt of an LDS Zn zone
__device__ __forceinline__ void lds_transpose(const u16* Z, u16* Pt, int lane){
#pragma unroll
  for(int g = 0; g < 8; g++){
    short8 f = lds_frag(Z, lane, g*8);
#pragma unroll
    for(int j = 0; j < 8; j++) Pt[swz(g*8 + j, lane)] = (u16)f[j];
  }
}

__device__ __forceinline__ float wave_max(float mx){
  for(int off = 32; off; off >>= 1) mx = fmaxf(mx, __shfl_xor(mx, off, 64));
  return mx;
}
__device__ __forceinline__ int norm_es(const f32x4 (&C)[4][4], float& s){
  float mx = 0.f;
#pragma unroll
  for(int i = 0; i < 4; i++)
#pragma unroll
    for(int j = 0; j < 4; j++)
#pragma unroll
      for(int t = 0; t < 4; t++) mx = fmaxf(mx, C[i][j][t]);   // entries all positive
  mx = wave_max(mx);
  int e; (void)frexpf(mx, &e);
  s = ldexpf(1.f, -e);
  return e;
}

// ---------- coherent partial barriers (per-XCD L2 NOT coherent: poll with agent-scope atomics) ----------
__device__ __forceinline__ void arrive(int* c){
  __syncthreads();
  if(threadIdx.x == 0){
    __threadfence();
    __hip_atomic_fetch_add(c, 1, __ATOMIC_RELEASE, __HIP_MEMORY_SCOPE_AGENT);
  }
}
__device__ __forceinline__ void wait_ge(int* c, int target){
  if(threadIdx.x == 0){
    while(__hip_atomic_load(c, __ATOMIC_ACQUIRE, __HIP_MEMORY_SCOPE_AGENT) < target)
      __builtin_amdgcn_s_sleep(4);
    __threadfence();
  }
  __syncthreads();
}

// power-iteration stages (one Kraus op per wave, K frags in regs)
__device__ __forceinline__ void pw_stages(const short8 (&Kf)[2][4], const u16* rho, u16* zw,
                                          int m16, int q, int lane){
  short8 Ar[2][4];
#pragma unroll
  for(int ks = 0; ks < 2; ks++)
#pragma unroll
    for(int t = 0; t < 4; t++) Ar[ks][t] = lds_frag(rho, t*16 + m16, ks*32 + q*8);
  f32x4 C[4][4];
#pragma unroll
  for(int i = 0; i < 4; i++)
#pragma unroll
    for(int j = 0; j < 4; j++) C[i][j] = f32x4{0.f,0.f,0.f,0.f};
#pragma unroll
  for(int ks = 0; ks < 2; ks++)
#pragma unroll
    for(int i = 0; i < 4; i++)
#pragma unroll
      for(int j = 0; j < 4; j++)
        C[i][j] = mfma_bf16(Ar[ks][i], Kf[ks][j], C[i][j]);
  write_CT_lds(zw, lane, C);            // zw = Kw*rho (rho symmetric)
  short8 Bt[2][4];
#pragma unroll
  for(int ks = 0; ks < 2; ks++)
#pragma unroll
    for(int t = 0; t < 4; t++) Bt[ks][t] = lds_frag(zw, t*16 + m16, ks*32 + q*8);
#pragma unroll
  for(int i = 0; i < 4; i++)
#pragma unroll
    for(int j = 0; j < 4; j++) C[i][j] = f32x4{0.f,0.f,0.f,0.f};
#pragma unroll
  for(int ks = 0; ks < 2; ks++)
#pragma unroll
    for(int i = 0; i < 4; i++)
#pragma unroll
      for(int j = 0; j < 4; j++)
        C[i][j] = mfma_bf16(Kf[ks][i], Bt[ks][j], C[i][j]);
  write_CT_lds(zw, lane, C);            // zone_w = Kw*rho*Kw^T
}

// ==================== the single kernel ====================
// blocks 0,1: power iteration (no phase-A dependency — overlaps phase A)
// blocks 2..129: phase A (node b-2: 128 seq-mats, 8 waves x chain-16 + combine) -> Nbuf, arrive c1
// blocks 130..137: wait c1==128, combine 16 nodes -> M2buf[b-130], arrive c2
// block 1 also: lambda + rhoL, arrive c2.  block 0: wait c2==9, final combine + contraction.
__global__ __launch_bounds__(512, 2) void kall(const float* __restrict__ K, const int* __restrict__ seq,
                                               u16* __restrict__ Nbuf, u16* __restrict__ M2buf,
                                               int* __restrict__ Sarr, int* __restrict__ Earr,
                                               float* __restrict__ rhoR, float* __restrict__ rhoL,
                                               float* __restrict__ muv, int* __restrict__ bar,
                                               float* __restrict__ outp){
  __shared__ __align__(16) u16 Kl[8*4096];     // bf16 K matrices (Zn swizzled)
  __shared__ __align__(16) u16 zones[8*4096];  // per-wave work zones
  __shared__ __align__(16) u16 rhoZ[4096];
  __shared__ float redf[8];
  __shared__ int exps[8];
  __shared__ float sh_t2;
  __shared__ int sh_S;
  const int tid = threadIdx.x, lane = tid & 63, wave = tid >> 6, b = blockIdx.x;
  const int m16 = lane & 15, q = lane >> 4;
  u16* zw = zones + wave*4096;

  if(b < 130){
    // stage K[wave] fp32 -> Kl zone (Zn swizzled); lane owns row = lane
#pragma unroll
    for(int g = 0; g < 8; g++){
      const float* p = K + (size_t)wave*4096 + lane*64 + g*8;
      float4 a = *(const float4*)p, c = *(const float4*)(p + 4);
      u32x4 u = { pack2bf(a.x,a.y), pack2bf(a.z,a.w), pack2bf(c.x,c.y), pack2bf(c.z,c.w) };
      *(short8*)(Kl + wave*4096 + lane*64 + ((g ^ (lane & 7)) << 3)) = __builtin_bit_cast(short8, u);
    }
  }

  if(b >= 2 && b < 130){
    // ================= PHASE A: chain-16 per wave, combine 8 -> node =================
    const int node = b - 2;
    int sv = (lane < 16) ? seq[node*128 + wave*16 + lane] : 0;
    __syncthreads();
    int s0 = __shfl(sv, 0, 64);
    lds_transpose(Kl + s0*4096, zw, lane);
    f32x4 C[4][4];
    short8 Af[2][4];
#pragma unroll 1
    for(int j = 1; j < 16; j++){
      int sj = __shfl(sv, j, 64);
      ld_zn_frags(Kl + sj*4096, m16, q, Af);
      chain_step_A(Af, zw, lane, C, j < 15);
    }
    float s; int e = norm_es(C, s);
    if(!(wave & 1)) write_CT_lds_s(zw, lane, C, s);   // even wave -> Zt
    else            scatter_C_rm(zw, lane, C, s);     // odd wave  -> Zn
    if(lane == 0) exps[wave] = e;
    __syncthreads();
    if(wave < 4){                                      // combine L1
      short8 Aa[2][4];
      ld_zn_frags(zones + (2*wave + 1)*4096, m16, q, Aa);
      f32x4 Y[4][4];
      bool e2 = !(wave & 1);
      chain_step_A(Aa, zones + 2*wave*4096, lane, Y, e2);
      if(!e2) scatter_C_rm(zones + 2*wave*4096, lane, Y, 1.f);
    }
    __syncthreads();
    if(wave < 2){                                      // combine L2
      short8 Aa[2][4];
      ld_zn_frags(zones + (4*wave + 2)*4096, m16, q, Aa);
      f32x4 Y[4][4];
      chain_step_A(Aa, zones + 4*wave*4096, lane, Y, wave == 0);
      if(wave == 1) scatter_C_rm(zones + 4*4096, lane, Y, 1.f);
    }
    __syncthreads();
    if(wave == 0){                                     // combine L3 + norm
      short8 Aa[2][4];
      ld_zn_frags(zones + 4*4096, m16, q, Aa);
      f32x4 M[4][4];
      chain_step_A(Aa, zones, lane, M, false);
      float sr; int er = norm_es(M, sr);
      scatter_C_rm(zones, lane, M, sr);
      if(lane == 0){
        int ss = er;
#pragma unroll
        for(int w = 0; w < 8; w++) ss += exps[w];
        Sarr[node] = ss;
      }
    }
    __syncthreads();
    {
      int row = tid >> 3, c0 = (tid & 7)*8;
      *(short8*)(Nbuf + (size_t)node*4096 + row*64 + c0) = lds_frag(zones, row, c0);
    }
    arrive(bar);                                       // c1
  } else if(b < 2){
    // ================= POWER ITERATION (overlaps phase A) =================
    const bool left = (b == 1);
    __syncthreads();
    short8 Kf[2][4];
    if(!left){
      ld_zn_frags(Kl + wave*4096, m16, q, Kf);
    } else {
#pragma unroll
      for(int ks = 0; ks < 2; ks++)
#pragma unroll
        for(int t = 0; t < 4; t++){
          short8 v;
#pragma unroll
          for(int j = 0; j < 8; j++) v[j] = (short)Kl[wave*4096 + swz(ks*32 + q*8 + j, t*16 + m16)];
          Kf[ks][t] = v;
        }
    }
    const int row = tid >> 3, k0 = (tid & 7)*8;
    const int rpos = row*64 + (((tid & 7) ^ (row & 7)) << 3);
    {
      short8 bb;
#pragma unroll
      for(int j = 0; j < 8; j++) bb[j] = (row == k0 + j) ? (short)f2bf(1.f/64.f) : (short)0;
      *(short8*)(rhoZ + rpos) = bb;
    }
    __syncthreads();
    const float S13 = 1.f/8192.f;        // fixed per-iter scale (lambda ~ 2^13)
#pragma unroll
    for(int it = 0; it < POWER_ITERS; it++){
      pw_stages(Kf, rhoZ, zw, m16, q, lane);
      __syncthreads();
      float v[8];
#pragma unroll
      for(int j2 = 0; j2 < 8; j2++) v[j2] = 0.f;
#pragma unroll
      for(int z = 0; z < 8; z++){
        short8 f = lds_frag(zones + z*4096, row, k0);
#pragma unroll
        for(int j2 = 0; j2 < 8; j2++) v[j2] += bf2f((u16)f[j2]);
      }
      if(it != POWER_ITERS - 1){
        u32x4 u = { pack2bf(v[0]*S13, v[1]*S13), pack2bf(v[2]*S13, v[3]*S13),
                    pack2bf(v[4]*S13, v[5]*S13), pack2bf(v[6]*S13, v[7]*S13) };
        *(short8*)(rhoZ + rpos) = __builtin_bit_cast(short8, u);
        __syncthreads();
      } else {
        float pd = (k0 <= row && row < k0 + 8) ? v[row - k0] : 0.f;
        for(int off = 32; off; off >>= 1) pd += __shfl_xor(pd, off, 64);
        if(lane == 0) redf[wave] = pd;
        __syncthreads();
        float tr = 0.f;
#pragma unroll
        for(int w = 0; w < 8; w++) tr += redf[w];
        float inv = 1.f/tr;
        float* ro = left ? rhoL : rhoR;
#pragma unroll
        for(int j2 = 0; j2 < 8; j2++) ro[row*64 + k0 + j2] = v[j2]*inv;
        u32x4 u = { pack2bf(v[0]*inv, v[1]*inv), pack2bf(v[2]*inv, v[3]*inv),
                    pack2bf(v[4]*inv, v[5]*inv), pack2bf(v[6]*inv, v[7]*inv) };
        *(short8*)(rhoZ + rpos) = __builtin_bit_cast(short8, u);   // normalized bf16 in LDS
      }
    }
    __syncthreads();
    if(left){
      // lambda = tr(rho_l * sum_a K_a K_a^T); wave a handles K_a
      short8 Ka[2][4];
      ld_zn_frags(Kl + wave*4096, m16, q, Ka);
      f32x4 G[4][4];
#pragma unroll
      for(int i = 0; i < 4; i++)
#pragma unroll
        for(int j = 0; j < 4; j++) G[i][j] = f32x4{0.f,0.f,0.f,0.f};
#pragma unroll
      for(int ks = 0; ks < 2; ks++)
#pragma unroll
        for(int i = 0; i < 4; i++)
#pragma unroll
          for(int j = 0; j < 4; j++)
            G[i][j] = mfma_bf16(Ka[ks][i], Ka[ks][j], G[i][j]);
      float lp = 0.f;
#pragma unroll
      for(int i = 0; i < 4; i++)
#pragma unroll
        for(int j = 0; j < 4; j++)
#pragma unroll
          for(int t = 0; t < 4; t++){
            int r = i*16 + q*4 + t, c = j*16 + m16;
            lp += G[i][j][t] * bf2f(rhoZ[swz(r, c)]);
          }
      for(int off = 32; off; off >>= 1) lp += __shfl_xor(lp, off, 64);
      if(lane == 0) redf[wave] = lp;
      __syncthreads();
      if(tid == 0){
        float m = 0.f;
#pragma unroll
        for(int w = 0; w < 8; w++) m += redf[w];
        muv[0] = m;
      }
      arrive(bar + 1);                                 // c2
    }
    if(!left){
      // ================= FINAL (block 0) =================
      wait_ge(bar + 1, 9);
      // round 1 (waves 0-3): X_w = M2[2w+1]*M2[2w]; side jobs on waves 4-6
      if(wave < 4){
        short8 Af[2][4];
        f32x4 C[4][4];
        ld_bf16_frags(M2buf + (size_t)(2*wave + 1)*4096, m16, q, Af);
        load_Pt_transpose(M2buf + (size_t)(2*wave)*4096, zw, lane);
        bool ev = !(wave & 1);
        chain_step_A(Af, zw, lane, C, ev);
        if(!ev) scatter_C_rm(zw, lane, C, 1.f);
      } else if(wave == 4){
        // rho_l fp32 global -> bf16 Zn at Kl+4096
#pragma unroll
        for(int g = 0; g < 8; g++){
          const float* p = rhoL + lane*64 + g*8;
          float4 a = *(const float4*)p, c = *(const float4*)(p + 4);
          u32x4 u = { pack2bf(a.x,a.y), pack2bf(a.z,a.w), pack2bf(c.x,c.y), pack2bf(c.z,c.w) };
          *(short8*)(Kl + 4096 + lane*64 + ((g ^ (lane & 7)) << 3)) = __builtin_bit_cast(short8, u);
        }
      } else if(wave == 5){
        float t2 = 0.f;
        for(int j = 0; j < 64; j++){
          int idx = lane + 64*j;
          t2 += rhoR[idx] * rhoL[idx];
        }
        for(int off = 32; off; off >>= 1) t2 += __shfl_xor(t2, off, 64);
        if(lane == 0) sh_t2 = t2;
      } else if(wave == 6){
        int s = Sarr[lane] + Sarr[lane + 64];
        if(lane < 8) s += Earr[lane];
        for(int off = 32; off; off >>= 1) s += __shfl_xor(s, off, 64);
        if(lane == 0) sh_S = s;
      }
      __syncthreads();
      // round 2 (waves 0,1)
      if(wave < 2){
        short8 Aa[2][4];
        f32x4 Y[4][4];
        ld_zn_frags(zones + (2*wave + 1)*4096, m16, q, Aa);
        chain_step_A(Aa, zones + 2*wave*4096, lane, Y, wave == 0);
        if(wave == 1) scatter_C_rm(zones + 2*4096, lane, Y, 1.f);
      }
      __syncthreads();
      // round 3 + contraction (wave 0)
      if(wave == 0){
        short8 Aa[2][4];
        f32x4 C[4][4];
        ld_zn_frags(zones + 2*4096, m16, q, Aa);
        chain_step_A(Aa, zones, lane, C, false);
        float sM; int eM = norm_es(C, sM);
        u16* Pm = zones + 1*4096;
        scatter_C_rm(Pm, lane, C, sM);               // M (Zn)

        // U = M * rho_r  (rho_r bf16 in rhoZ, symmetric)
        short8 Ua[2][4], Ub[2][4];
        ld_zn_frags(Pm, m16, q, Ua);
        ld_zn_frags(rhoZ, m16, q, Ub);
#pragma unroll
        for(int i = 0; i < 4; i++)
#pragma unroll
          for(int j = 0; j < 4; j++) C[i][j] = f32x4{0.f,0.f,0.f,0.f};
#pragma unroll
        for(int ks = 0; ks < 2; ks++)
#pragma unroll
          for(int i = 0; i < 4; i++)
#pragma unroll
            for(int j = 0; j < 4; j++)
              C[i][j] = mfma_bf16(Ua[ks][i], Ub[ks][j], C[i][j]);
        write_CT_lds(zones + 3*4096, lane, C);       // U^T

        // D2 = rho_l * U
        ld_zn_frags(Kl + 4096, m16, q, Ua);
#pragma unroll
        for(int ks = 0; ks < 2; ks++)
#pragma unroll
          for(int t = 0; t < 4; t++) Ub[ks][t] = lds_frag(zones + 3*4096, t*16 + m16, ks*32 + q*8);
#pragma unroll
        for(int i = 0; i < 4; i++)
#pragma unroll
          for(int j = 0; j < 4; j++) C[i][j] = f32x4{0.f,0.f,0.f,0.f};
#pragma unroll
        for(int ks = 0; ks < 2; ks++)
#pragma unroll
          for(int i = 0; i < 4; i++)
#pragma unroll
            for(int j = 0; j < 4; j++)
              C[i][j] = mfma_bf16(Ua[ks][i], Ub[ks][j], C[i][j]);

        // t1 = sum_ij D2_ij * M_ij
        float part = 0.f;
#pragma unroll
        for(int i = 0; i < 4; i++)
#pragma unroll
          for(int j = 0; j < 4; j++)
#pragma unroll
            for(int t = 0; t < 4; t++){
              int r = i*16 + q*4 + t, c = j*16 + m16;
              part += C[i][j][t] * bf2f(Pm[swz(r, c)]);
            }
        for(int off = 32; off; off >>= 1) part += __shfl_xor(part, off, 64);
        if(lane == 0){
          double t1  = (double)part;
          double lam = (double)muv[0];
          double S   = (double)sh_S + eM;
          double logp = 16384.0*log2(lam) - 2.0*S - log2(t1) + log2((double)sh_t2);
          outp[0] = (float)logp;
        }
      }
    }
  } else if(b < 138){
    // ================= COMBINE: 16 Nbuf nodes -> one M2 node =================
    wait_ge(bar, 128);
    const int idx = b - 130, nb = idx*16;
    short8 Af[2][4];
    ld_bf16_frags(Nbuf + (size_t)(nb + 2*wave + 1)*4096, m16, q, Af);
    load_Pt_transpose(Nbuf + (size_t)(nb + 2*wave)*4096, zw, lane);
    f32x4 C[4][4];
    bool ev = !(wave & 1);
    chain_step_A(Af, zw, lane, C, ev);
    if(!ev) scatter_C_rm(zw, lane, C, 1.f);
    __syncthreads();
    if(wave < 4){
      short8 Aa[2][4];
      f32x4 Y[4][4];
      ld_zn_frags(zones + (2*wave + 1)*4096, m16, q, Aa);
      bool e2 = !(wave & 1);
      chain_step_A(Aa, zones + 2*wave*4096, lane, Y, e2);
      if(!e2) scatter_C_rm(zones + 2*wave*4096, lane, Y, 1.f);
    }
    __syncthreads();
    if(wave < 2){
      short8 Aa[2][4];
      f32x4 Y[4][4];
      ld_zn_frags(zones + (4*wave + 2)*4096, m16, q, Aa);
      chain_step_A(Aa, zones + 4*wave*4096, lane, Y, wave == 0);
      if(wave == 1) scatter_C_rm(zones + 4*4096, lane, Y, 1.f);
    }
    __syncthreads();
    if(wave == 0){
      short8 Aa[2][4];
      f32x4 M[4][4];
      ld_zn_frags(zones + 4*4096, m16, q, Aa);
      chain_step_A(Aa, zones, lane, M, false);
      float sr; int er = norm_es(M, sr);
      scatter_C_rm(zones, lane, M, sr);
      if(lane == 0) Earr[idx] = er;
    }
    __syncthreads();
    {
      int row = tid >> 3, c0 = (tid & 7)*8;
      *(short8*)(M2buf + (size_t)idx*4096 + row*64 + c0) = lds_frag(zones, row, c0);
    }
    arrive(bar + 1);                                   // c2
  }
}

// ---------- launch ----------
extern "C" void kernel_launch(void* const* d_in, const int* in_sizes, int n_in,
                              void* d_out, int out_size, void* d_ws, size_t ws_size,
                              hipStream_t stream) {
  const float* K  = (const float*)d_in[0];   // (8,64,64) fp32
  const int* seq  = (const int*)d_in[1];     // (16384,) int32
  char* ws = (char*)d_ws;
  u16*   Nbuf  = (u16*)(ws);                   // 128 * 8KB = 1 MB
  u16*   M2buf = (u16*)(ws + 1048576);         // 8 * 8KB = 64 KB
  int*   Sarr  = (int*)(ws + 1114112);         // 128 ints
  int*   Earr  = (int*)(ws + 1114624);         // 8 ints
  float* rhoR  = (float*)(ws + 1115136);       // 16 KB
  float* rhoL  = (float*)(ws + 1131520);       // 16 KB
  float* muv   = (float*)(ws + 1147904);       // 1 float
  int*   bar   = (int*)(ws + 1147968);         // 2 ints (c1, c2)

  hipMemsetAsync(bar, 0, 8, stream);
  kall<<<256, 512, 0, stream>>>(K, seq, Nbuf, M2buf, Sarr, Earr, rhoR, rhoL, muv, bar,
                                (float*)d_out);
}